// Round 2
// baseline (457.109 us; speedup 1.0000x reference)
//
#include <hip/hip_runtime.h>

#define NB 128      // batch
#define NS 100      // samples
#define NPRED 24
#define NHID 256
#define NSTEPS 16
#define NCTX 96
// rows M = NS*NB = 12800; 16 rows per wave, 4 waves/block -> 200 blocks

typedef float f32x4 __attribute__((ext_vector_type(4)));
typedef short bf16x8 __attribute__((ext_vector_type(8)));

__device__ __forceinline__ unsigned short f2bf(float f) {
    union { float f; unsigned u; } v; v.f = f;
    return (unsigned short)((v.u + 0x7fffu + ((v.u >> 16) & 1u)) >> 16);
}
__device__ __forceinline__ unsigned pk2(float lo, float hi) {
    return (unsigned)f2bf(lo) | ((unsigned)f2bf(hi) << 16);
}
__device__ __forceinline__ bf16x8 mk8(unsigned a, unsigned b, unsigned c, unsigned d) {
    union { unsigned u[4]; bf16x8 v; } x;
    x.u[0] = a; x.u[1] = b; x.u[2] = c; x.u[3] = d;
    return x.v;
}

// k-slot permutation within a 32-wide k-block, position (lane l, elem e):
//   k_local = 16*(e>>2) + 4*(l>>4) + (e&3)
// Used consistently for ALL A (weight) and B (activation) fragments, so the
// result is correct for any lane-symmetric hardware k-map (bijection argument).

__global__ __launch_bounds__(256, 1) void fm_kernel(
    const float* __restrict__ past_target,
    const float* __restrict__ z0g,
    const float* __restrict__ W1, const float* __restrict__ b1,
    const float* __restrict__ W2, const float* __restrict__ b2,
    const float* __restrict__ W3, const float* __restrict__ b3,
    float* __restrict__ out) {
    // LDS: W2F 65536 ushorts + W3F 8192 ushorts = 147456 B
    __shared__ __attribute__((aligned(16))) unsigned short lds[73728];

    const int tid = threadIdx.x;

    // ---- stage permuted W2/W3 frag images into LDS (one-time) ----
    for (int idx = tid; idx < 65536; idx += 256) {
        int ks = idx >> 13, T = (idx >> 9) & 15, ll = (idx >> 3) & 63, e = idx & 7;
        int k = 32 * ks + 16 * (e >> 2) + 4 * (ll >> 4) + (e & 3);
        int m = 16 * T + (ll & 15);
        lds[idx] = f2bf(W2[k * NHID + m]);
    }
    for (int idx = tid; idx < 8192; idx += 256) {
        int ks = idx >> 10, T = (idx >> 9) & 1, ll = (idx >> 3) & 63, e = idx & 7;
        int k = 32 * ks + 16 * (e >> 2) + 4 * (ll >> 4) + (e & 3);
        int m = 16 * T + (ll & 15);
        lds[65536 + idx] = (m < NPRED) ? f2bf(W3[k * NPRED + m]) : (unsigned short)0;
    }

    const int wave = tid >> 6;
    const int l = tid & 63;
    const int q = l >> 4, p = l & 15;
    const int g = blockIdx.x * 4 + wave;   // 0..799
    const int R = g * 16 + p;              // global row 0..12799
    const int s = R >> 7, b = R & 127;

    // ---- per-lane loc (scale) ----
    const float* ctx = past_target + b * NCTX;
    float asum = 0.f;
    for (int k = 0; k < NCTX; k++) asum += fabsf(ctx[k]);
    float loc = fmaxf(asum / (float)NCTX, 1e-6f);
    float inv = 1.f / loc;

    // ---- fp32 context bias: cb[T] = b1[16T+4q..] + sum_k sctx[k]*W1[26+k][16T+4q..] ----
    f32x4 cb[16];
#pragma unroll
    for (int T = 0; T < 16; T++) cb[T] = *(const f32x4*)(b1 + 16 * T + 4 * q);
    for (int k = 0; k < NCTX; k++) {
        float sx = ctx[k] * inv;
        const f32x4* wr = (const f32x4*)(W1 + (26 + k) * NHID + 4 * q);
#pragma unroll
        for (int T = 0; T < 16; T++) {
            f32x4 w = wr[4 * T];
            cb[T].x += sx * w.x; cb[T].y += sx * w.y;
            cb[T].z += sx * w.z; cb[T].w += sx * w.w;
        }
    }

    // ---- W1z fragments in registers (rows 0..23 = z, 24 = t; 25.. excluded) ----
    bf16x8 w1f[16];
#pragma unroll
    for (int T = 0; T < 16; T++) {
        unsigned u[4];
#pragma unroll
        for (int ee = 0; ee < 4; ee++) {
            int e0 = 2 * ee, e1 = 2 * ee + 1;
            int k0 = 16 * (e0 >> 2) + 4 * q + (e0 & 3);
            int k1 = 16 * (e1 >> 2) + 4 * q + (e1 & 3);
            float v0 = (k0 <= 24) ? W1[k0 * NHID + 16 * T + p] : 0.f;
            float v1 = (k1 <= 24) ? W1[k1 * NHID + 16 * T + p] : 0.f;
            u[ee] = pk2(v0, v1);
        }
        w1f[T] = mk8(u[0], u[1], u[2], u[3]);
    }

    // ---- z state in C'-layout: zs0 = ch 4q..4q+3, zs1 = ch 16+4q.. (q<2), else 0 ----
    f32x4 zs0, zs1;
    {
        const f32x4* zr = (const f32x4*)(z0g + R * NPRED);
        zs0 = zr[q];
        f32x4 zz = {0.f, 0.f, 0.f, 0.f};
        zs1 = zz;
        if (q < 2) zs1 = zr[4 + q];
    }

    // ---- bias A-frag pieces (k-slot 0 lives at lanes l<16, elem 0) ----
    unsigned b2v[16];
#pragma unroll
    for (int T = 0; T < 16; T++)
        b2v[T] = (l < 16) ? (unsigned)f2bf(b2[16 * T + p]) : 0u;
    unsigned b3v0 = (l < 16) ? (unsigned)f2bf(b3[p]) : 0u;            // p<24 always
    unsigned b3v1 = (l < 16 && p < 8) ? (unsigned)f2bf(b3[16 + p]) : 0u;
    const unsigned bone = (l < 16) ? 0x3f80u : 0u;  // bf16 1.0 at slot (e=0)

    __syncthreads();

    const float dt = 1.f / (float)NSTEPS;
#pragma unroll 1
    for (int step = 0; step < NSTEPS; step++) {
        float t = 1.f - (float)step * dt;
        // B-frag from z; channel 24 (q==2, e==4) carries t
        float z10 = (q == 2) ? t : zs1.x;
        bf16x8 bz = mk8(pk2(zs0.x, zs0.y), pk2(zs0.z, zs0.w),
                        pk2(z10, zs1.y), pk2(zs1.z, zs1.w));

        // ---- layer 1: h1 = relu(z@W1z + t*w1t + cbias) ----
        unsigned bh[32];
#pragma unroll
        for (int T = 0; T < 16; T++) {
            f32x4 h = __builtin_amdgcn_mfma_f32_16x16x32_bf16(w1f[T], bz, cb[T], 0, 0, 0);
            h.x = fmaxf(h.x, 0.f); h.y = fmaxf(h.y, 0.f);
            h.z = fmaxf(h.z, 0.f); h.w = fmaxf(h.w, 0.f);
            bh[2 * T]     = pk2(h.x, h.y);
            bh[2 * T + 1] = pk2(h.z, h.w);
        }

        // ---- layer 2: h2 = relu(h1@W2 + b2) ----
        unsigned bh2[32];
#pragma unroll
        for (int T = 0; T < 16; T++) {
            f32x4 acc = {0.f, 0.f, 0.f, 0.f};
#pragma unroll
            for (int ks = 0; ks < 8; ks++) {
                bf16x8 a = *(const bf16x8*)(lds + ((ks * 16 + T) * 64 + l) * 8);
                bf16x8 bb = mk8(bh[4 * ks], bh[4 * ks + 1], bh[4 * ks + 2], bh[4 * ks + 3]);
                acc = __builtin_amdgcn_mfma_f32_16x16x32_bf16(a, bb, acc, 0, 0, 0);
            }
            acc = __builtin_amdgcn_mfma_f32_16x16x32_bf16(
                mk8(b2v[T], 0u, 0u, 0u), mk8(bone, 0u, 0u, 0u), acc, 0, 0, 0);
            acc.x = fmaxf(acc.x, 0.f); acc.y = fmaxf(acc.y, 0.f);
            acc.z = fmaxf(acc.z, 0.f); acc.w = fmaxf(acc.w, 0.f);
            bh2[2 * T]     = pk2(acc.x, acc.y);
            bh2[2 * T + 1] = pk2(acc.z, acc.w);
        }

        // ---- layer 3: v = h2@W3 + b3 (m>=24 rows are zero-padded in frags) ----
        f32x4 v0 = {0.f, 0.f, 0.f, 0.f}, v1 = {0.f, 0.f, 0.f, 0.f};
#pragma unroll
        for (int ks = 0; ks < 8; ks++) {
            bf16x8 bb = mk8(bh2[4 * ks], bh2[4 * ks + 1], bh2[4 * ks + 2], bh2[4 * ks + 3]);
            bf16x8 a0 = *(const bf16x8*)(lds + 65536 + ((ks * 2 + 0) * 64 + l) * 8);
            bf16x8 a1 = *(const bf16x8*)(lds + 65536 + ((ks * 2 + 1) * 64 + l) * 8);
            v0 = __builtin_amdgcn_mfma_f32_16x16x32_bf16(a0, bb, v0, 0, 0, 0);
            v1 = __builtin_amdgcn_mfma_f32_16x16x32_bf16(a1, bb, v1, 0, 0, 0);
        }
        v0 = __builtin_amdgcn_mfma_f32_16x16x32_bf16(
            mk8(b3v0, 0u, 0u, 0u), mk8(bone, 0u, 0u, 0u), v0, 0, 0, 0);
        v1 = __builtin_amdgcn_mfma_f32_16x16x32_bf16(
            mk8(b3v1, 0u, 0u, 0u), mk8(bone, 0u, 0u, 0u), v1, 0, 0, 0);

        // ---- Euler update (pad channels have v==0, stay 0) ----
        zs0.x -= dt * v0.x; zs0.y -= dt * v0.y; zs0.z -= dt * v0.z; zs0.w -= dt * v0.w;
        zs1.x -= dt * v1.x; zs1.y -= dt * v1.y; zs1.z -= dt * v1.z; zs1.w -= dt * v1.w;
    }

    // ---- store: out[b][s][c] = z[c] * loc ----
    float* op = out + b * (NS * NPRED) + s * NPRED;
    f32x4 o0 = zs0 * loc;
    *(f32x4*)(op + 4 * q) = o0;
    if (q < 2) {
        f32x4 o1 = zs1 * loc;
        *(f32x4*)(op + 16 + 4 * q) = o1;
    }
}

extern "C" void kernel_launch(void* const* d_in, const int* in_sizes, int n_in,
                              void* d_out, int out_size, void* d_ws, size_t ws_size,
                              hipStream_t stream) {
    const float* past_target = (const float*)d_in[0];
    // d_in[1] past_observed_values: not used by the reference math
    const float* z0 = (const float*)d_in[2];
    const float* W1 = (const float*)d_in[3];
    const float* b1 = (const float*)d_in[4];
    const float* W2 = (const float*)d_in[5];
    const float* b2 = (const float*)d_in[6];
    const float* W3 = (const float*)d_in[7];
    const float* b3 = (const float*)d_in[8];

    fm_kernel<<<200, 256, 0, stream>>>(past_target, z0, W1, b1, W2, b2, W3, b3,
                                       (float*)d_out);
}